// Round 1
// baseline (1847.614 us; speedup 1.0000x reference)
//
#include <hip/hip_runtime.h>

// GraphRegressorV2 — round 1: correct fp32 implementation.
// Pipeline: node embed -> CSR build -> edge msg aggregate (algebraically
// pushed through proj: segsum(relu(eaW+b))@projW + cnt*proj_b) ->
// 3x (GEMM + gather-aggregate) -> attn pool -> head.

// ---------------- node embedding ----------------
__global__ void node_embed_kernel(const float* __restrict__ x,
                                  const float* __restrict__ coord_W, const float* __restrict__ coord_b,
                                  const float* __restrict__ node_W, const float* __restrict__ node_b,
                                  float* __restrict__ x_emb, int N) {
  int idx = blockIdx.x * 256 + threadIdx.x;
  if (idx >= N * 256) return;
  int n = idx >> 8, ch = idx & 255;
  const float* xr = x + n * 9;
  float acc;
  if (ch < 128) {
    acc = coord_b[ch];
#pragma unroll
    for (int k = 0; k < 3; k++) acc = fmaf(xr[k], coord_W[k * 128 + ch], acc);
  } else {
    int c = ch - 128;
    acc = node_b[c];
#pragma unroll
    for (int k = 0; k < 6; k++) acc = fmaf(xr[3 + k], node_W[k * 128 + c], acc);
  }
  x_emb[idx] = fmaxf(acc, 0.f);
}

// ---------------- CSR build ----------------
__global__ void count_kernel(const int* __restrict__ col, int* __restrict__ cnt, int E) {
  int e = blockIdx.x * 256 + threadIdx.x;
  if (e < E) atomicAdd(&cnt[col[e]], 1);
}

// single-block exclusive scan over cnt -> rowstart; also dnorm + cursor init
__global__ void scan_kernel(const int* __restrict__ cnt, int* __restrict__ rowstart,
                            float* __restrict__ dnorm, int* __restrict__ cursor, int n) {
  __shared__ int sums[1024];
  int t = threadIdx.x;
  int chunk = (n + 1023) / 1024;
  int start = t * chunk;
  int end = min(start + chunk, n);
  int s = 0;
  for (int i = start; i < end; i++) s += cnt[i];
  sums[t] = s;
  for (int off = 1; off < 1024; off <<= 1) {
    __syncthreads();
    int v = (t >= off) ? sums[t - off] : 0;
    __syncthreads();
    sums[t] += v;
  }
  __syncthreads();
  int base = (t == 0) ? 0 : sums[t - 1];
  for (int i = start; i < end; i++) {
    rowstart[i] = base;
    int c = cnt[i];
    base += c;
    dnorm[i] = rsqrtf((float)(c + 1));  // +1 self-loop
    cursor[i] = 0;
  }
  if (t == 1023) rowstart[n] = sums[1023];
}

__global__ void scatter_kernel(const int* __restrict__ row, const int* __restrict__ col,
                               const int* __restrict__ rowstart, int* __restrict__ cursor,
                               const float* __restrict__ dnorm,
                               int* __restrict__ csr_eid, int* __restrict__ csr_row,
                               float* __restrict__ csr_efac, int E) {
  int e = blockIdx.x * 256 + threadIdx.x;
  if (e >= E) return;
  int c = col[e], r = row[e];
  int p = atomicAdd(&cursor[c], 1);
  int slot = rowstart[c] + p;
  csr_eid[slot] = e;
  csr_row[slot] = r;
  csr_efac[slot] = dnorm[r] * dnorm[c];
}

// ---------------- edge message aggregate (pre-projection) ----------------
// msg128[n] = sum_{e: col(e)=n} relu(edge_attr[e] @ edge_W + edge_b)
__global__ void edge_msg_kernel(const float* __restrict__ edge_attr,
                                const int* __restrict__ csr_eid, const int* __restrict__ rowstart,
                                const float* __restrict__ edge_W, const float* __restrict__ edge_b,
                                float* __restrict__ msg128, int N) {
  int node = blockIdx.x;
  int ch = threadIdx.x;  // 128 threads
  __shared__ float sW[8 * 128];
  __shared__ float sb[128];
  for (int i = ch; i < 8 * 128; i += 128) sW[i] = edge_W[i];
  sb[ch] = edge_b[ch];
  __syncthreads();
  float acc = 0.f;
  int s0 = rowstart[node], s1 = rowstart[node + 1];
  for (int s = s0; s < s1; s++) {
    int e = csr_eid[s];
    const float* ea = edge_attr + (size_t)e * 8;
    float t = sb[ch];
#pragma unroll
    for (int k = 0; k < 8; k++) t = fmaf(ea[k], sW[k * 128 + ch], t);
    acc += fmaxf(t, 0.f);
  }
  msg128[(size_t)node * 128 + ch] = acc;
}

// node_msg[n] = msg128[n] @ proj_W + cnt[n]*proj_b   ([N,128]@[128,256])
__global__ void __launch_bounds__(256) proj_gemm_kernel(
    const float* __restrict__ msg128, const float* __restrict__ proj_W,
    const float* __restrict__ proj_b, const int* __restrict__ cnt,
    float* __restrict__ node_msg, int N) {
  __shared__ __align__(16) float xs[16][128];
  int ch = threadIdx.x;
  int n0 = blockIdx.x * 16;
  for (int idx = ch; idx < 16 * 128; idx += 256) {
    int r = idx >> 7, k = idx & 127;
    int n = n0 + r;
    xs[r][k] = (n < N) ? msg128[(size_t)n * 128 + k] : 0.f;
  }
  __syncthreads();
  float acc[16];
#pragma unroll
  for (int r = 0; r < 16; r++) acc[r] = 0.f;
  const float4* xsv = reinterpret_cast<const float4*>(&xs[0][0]);
  for (int k4 = 0; k4 < 32; k4++) {
    float w0 = proj_W[(k4 * 4 + 0) * 256 + ch];
    float w1 = proj_W[(k4 * 4 + 1) * 256 + ch];
    float w2 = proj_W[(k4 * 4 + 2) * 256 + ch];
    float w3 = proj_W[(k4 * 4 + 3) * 256 + ch];
#pragma unroll
    for (int r = 0; r < 16; r++) {
      float4 xv = xsv[r * 32 + k4];
      acc[r] = fmaf(xv.x, w0, acc[r]);
      acc[r] = fmaf(xv.y, w1, acc[r]);
      acc[r] = fmaf(xv.z, w2, acc[r]);
      acc[r] = fmaf(xv.w, w3, acc[r]);
    }
  }
  float pb = proj_b[ch];
#pragma unroll
  for (int r = 0; r < 16; r++) {
    int n = n0 + r;
    if (n < N) node_msg[(size_t)n * 256 + ch] = acc[r] + (float)cnt[n] * pb;
  }
}

// h = (x_emb + node_msg) @ W   ([N,256]@[256,256])
__global__ void __launch_bounds__(256) gcn_gemm_kernel(
    const float* __restrict__ X, const float* __restrict__ M,
    const float* __restrict__ W, float* __restrict__ Hout, int N) {
  __shared__ __align__(16) float xs[16][256];
  int ch = threadIdx.x;
  int n0 = blockIdx.x * 16;
  for (int idx = ch; idx < 16 * 256; idx += 256) {
    int r = idx >> 8, k = idx & 255;
    int n = n0 + r;
    xs[r][k] = (n < N) ? X[(size_t)n * 256 + k] + M[(size_t)n * 256 + k] : 0.f;
  }
  __syncthreads();
  float acc[16];
#pragma unroll
  for (int r = 0; r < 16; r++) acc[r] = 0.f;
  const float4* xsv = reinterpret_cast<const float4*>(&xs[0][0]);
  for (int k4 = 0; k4 < 64; k4++) {
    float w0 = W[(k4 * 4 + 0) * 256 + ch];
    float w1 = W[(k4 * 4 + 1) * 256 + ch];
    float w2 = W[(k4 * 4 + 2) * 256 + ch];
    float w3 = W[(k4 * 4 + 3) * 256 + ch];
#pragma unroll
    for (int r = 0; r < 16; r++) {
      float4 xv = xsv[r * 64 + k4];
      acc[r] = fmaf(xv.x, w0, acc[r]);
      acc[r] = fmaf(xv.y, w1, acc[r]);
      acc[r] = fmaf(xv.z, w2, acc[r]);
      acc[r] = fmaf(xv.w, w3, acc[r]);
    }
  }
#pragma unroll
  for (int r = 0; r < 16; r++) {
    int n = n0 + r;
    if (n < N) Hout[(size_t)n * 256 + ch] = acc[r];
  }
}

// x_emb[n] = sum_{slots} h[csr_row]*efac + h[n]*dnorm[n]^2 + b  (optional relu)
__global__ void gcn_agg_kernel(const float* __restrict__ h, const int* __restrict__ csr_row,
                               const float* __restrict__ csr_efac, const int* __restrict__ rowstart,
                               const float* __restrict__ dnorm, const float* __restrict__ b,
                               float* __restrict__ x_emb, int do_relu, int N) {
  int node = blockIdx.x;
  int ch = threadIdx.x;  // 256
  float dn = dnorm[node];
  float acc = h[(size_t)node * 256 + ch] * dn * dn;
  int s0 = rowstart[node], s1 = rowstart[node + 1];
  for (int s = s0; s < s1; s++) {
    int r = csr_row[s];
    float f = csr_efac[s];
    acc = fmaf(h[(size_t)r * 256 + ch], f, acc);
  }
  acc += b[ch];
  if (do_relu) acc = fmaxf(acc, 0.f);
  x_emb[(size_t)node * 256 + ch] = acc;
}

// ---------------- attention pooling ----------------
__global__ void scores_kernel(const float* __restrict__ x_emb, const float* __restrict__ attn_w,
                              const float* __restrict__ attn_b, float* __restrict__ scores, int N) {
  int tid = blockIdx.x * 256 + threadIdx.x;
  int node = tid >> 6;
  int lane = tid & 63;
  if (node >= N) return;
  float s = 0.f;
  for (int k = lane; k < 256; k += 64) s = fmaf(x_emb[(size_t)node * 256 + k], attn_w[k], s);
#pragma unroll
  for (int off = 32; off; off >>= 1) s += __shfl_down(s, off);
  if (lane == 0) scores[node] = s + attn_b[0];
}

__global__ void gse_kernel(const int* __restrict__ batch, int* __restrict__ gs,
                           int* __restrict__ ge, int N) {
  int i = blockIdx.x * 256 + threadIdx.x;
  if (i >= N) return;
  int g = batch[i];
  atomicMin(&gs[g], i);
  atomicMax(&ge[g], i);
}

__global__ void pool_kernel(const float* __restrict__ x_emb, const float* __restrict__ scores,
                            const int* __restrict__ gs, const int* __restrict__ ge,
                            float* __restrict__ graph_emb) {
  int g = blockIdx.x;
  int tid = threadIdx.x;  // 256
  __shared__ float red[256];
  __shared__ float wts[256];
  int s0 = gs[g], e1 = ge[g];
  if (s0 > e1) {  // empty graph -> segment sums are 0
    graph_emb[(size_t)g * 256 + tid] = 0.f;
    return;
  }
  int s1 = e1 + 1;
  // max
  float m = -1e30f;
  for (int i = s0 + tid; i < s1; i += 256) m = fmaxf(m, scores[i]);
  red[tid] = m;
  __syncthreads();
  for (int off = 128; off; off >>= 1) {
    if (tid < off) red[tid] = fmaxf(red[tid], red[tid + off]);
    __syncthreads();
  }
  m = red[0];
  __syncthreads();
  // denom
  float dsum = 0.f;
  for (int i = s0 + tid; i < s1; i += 256) dsum += expf(scores[i] - m);
  red[tid] = dsum;
  __syncthreads();
  for (int off = 128; off; off >>= 1) {
    if (tid < off) red[tid] += red[tid + off];
    __syncthreads();
  }
  float denom = red[0];
  __syncthreads();
  // weighted sum (thread = channel)
  float acc = 0.f;
  for (int base = s0; base < s1; base += 256) {
    int i = base + tid;
    __syncthreads();
    wts[tid] = (i < s1) ? expf(scores[i] - m) : 0.f;
    __syncthreads();
    int lim = min(256, s1 - base);
    for (int j = 0; j < lim; j++)
      acc = fmaf(x_emb[(size_t)(base + j) * 256 + tid], wts[j], acc);
  }
  graph_emb[(size_t)g * 256 + tid] = acc / denom;
}

// ---------------- head ----------------
__global__ void head_kernel(const float* __restrict__ global_x, const float* __restrict__ graph_emb,
                            const float* __restrict__ W1, const float* __restrict__ b1,
                            const float* __restrict__ W2, const float* __restrict__ b2,
                            const float* __restrict__ fW1, const float* __restrict__ fb1,
                            const float* __restrict__ fW2, const float* __restrict__ fb2,
                            float* __restrict__ out) {
  int g = blockIdx.x;
  int ch = threadIdx.x;  // 256
  __shared__ float t1[256], g2s[256], t3s[256];
  float a = b1[ch];
  const float* gx = global_x + g * 16;
#pragma unroll
  for (int k = 0; k < 16; k++) a = fmaf(gx[k], W1[k * 256 + ch], a);
  t1[ch] = fmaxf(a, 0.f);
  __syncthreads();
  float bb = b2[ch];
  for (int k = 0; k < 256; k++) bb = fmaf(t1[k], W2[k * 256 + ch], bb);
  g2s[ch] = bb;
  __syncthreads();
  float c = fb1[ch];
  const float* ger = graph_emb + (size_t)g * 256;
  for (int k = 0; k < 256; k++) c = fmaf(ger[k], fW1[k * 256 + ch], c);
  for (int k = 0; k < 256; k++) c = fmaf(g2s[k], fW1[(256 + k) * 256 + ch], c);
  t3s[ch] = fmaxf(c, 0.f);
  __syncthreads();
  // reduce t3s[k]*fW2[k]
  t1[ch] = t3s[ch] * fW2[ch];
  __syncthreads();
  for (int off = 128; off; off >>= 1) {
    if (ch < off) t1[ch] += t1[ch + off];
    __syncthreads();
  }
  if (ch == 0) out[g] = t1[0] + fb2[0];
}

// ---------------- launch ----------------
extern "C" void kernel_launch(void* const* d_in, const int* in_sizes, int n_in,
                              void* d_out, int out_size, void* d_ws, size_t ws_size,
                              hipStream_t stream) {
  const float* x        = (const float*)d_in[0];
  const int*   ei       = (const int*)d_in[1];
  const int*   batch    = (const int*)d_in[2];
  const float* edge_attr= (const float*)d_in[3];
  const float* global_x = (const float*)d_in[4];
  const float* coord_W  = (const float*)d_in[5];
  const float* coord_b  = (const float*)d_in[6];
  const float* node_W   = (const float*)d_in[7];
  const float* node_b   = (const float*)d_in[8];
  const float* edge_W   = (const float*)d_in[9];
  const float* edge_b   = (const float*)d_in[10];
  const float* proj_W   = (const float*)d_in[11];
  const float* proj_b   = (const float*)d_in[12];
  const float* gcn_W    = (const float*)d_in[13];
  const float* gcn_b    = (const float*)d_in[14];
  const float* attn_w   = (const float*)d_in[15];
  const float* attn_b   = (const float*)d_in[16];
  const float* gmlp_W1  = (const float*)d_in[17];
  const float* gmlp_b1  = (const float*)d_in[18];
  const float* gmlp_W2  = (const float*)d_in[19];
  const float* gmlp_b2  = (const float*)d_in[20];
  const float* fc_W1    = (const float*)d_in[21];
  const float* fc_b1    = (const float*)d_in[22];
  const float* fc_W2    = (const float*)d_in[23];
  const float* fc_b2    = (const float*)d_in[24];

  const int N = in_sizes[0] / 9;
  const int E = in_sizes[3] / 8;
  const int G = in_sizes[4] / 16;

  char* w = (char*)d_ws;
  auto alloc = [&](size_t bytes) -> char* {
    char* p = w;
    w += (bytes + 255) & ~(size_t)255;
    return p;
  };
  float* x_emb    = (float*)alloc((size_t)N * 256 * 4);
  float* node_msg = (float*)alloc((size_t)N * 256 * 4);
  float* h        = (float*)alloc((size_t)N * 256 * 4);
  float* msg128   = h;  // alias: msg128 used only before h is needed
  int*   cnt      = (int*)alloc((size_t)N * 4);
  int*   rowstart = (int*)alloc((size_t)(N + 1) * 4);
  int*   cursor   = (int*)alloc((size_t)N * 4);
  float* dnorm    = (float*)alloc((size_t)N * 4);
  int*   csr_eid  = (int*)alloc((size_t)E * 4);
  int*   csr_row  = (int*)alloc((size_t)E * 4);
  float* csr_efac = (float*)alloc((size_t)E * 4);
  float* scores   = (float*)alloc((size_t)N * 4);
  int*   gs       = (int*)alloc((size_t)G * 4);
  int*   ge       = (int*)alloc((size_t)G * 4);
  float* graph_emb= (float*)alloc((size_t)G * 256 * 4);

  hipMemsetAsync(cnt, 0, (size_t)N * 4, stream);
  hipMemsetAsync(gs, 0x7f, (size_t)G * 4, stream);   // large positive
  hipMemsetAsync(ge, 0xff, (size_t)G * 4, stream);   // -1

  node_embed_kernel<<<(N * 256 + 255) / 256, 256, 0, stream>>>(
      x, coord_W, coord_b, node_W, node_b, x_emb, N);
  count_kernel<<<(E + 255) / 256, 256, 0, stream>>>(ei + E, cnt, E);
  scan_kernel<<<1, 1024, 0, stream>>>(cnt, rowstart, dnorm, cursor, N);
  scatter_kernel<<<(E + 255) / 256, 256, 0, stream>>>(
      ei, ei + E, rowstart, cursor, dnorm, csr_eid, csr_row, csr_efac, E);
  edge_msg_kernel<<<N, 128, 0, stream>>>(edge_attr, csr_eid, rowstart, edge_W, edge_b, msg128, N);
  proj_gemm_kernel<<<(N + 15) / 16, 256, 0, stream>>>(msg128, proj_W, proj_b, cnt, node_msg, N);
  for (int l = 0; l < 3; l++) {
    gcn_gemm_kernel<<<(N + 15) / 16, 256, 0, stream>>>(
        x_emb, node_msg, gcn_W + (size_t)l * 256 * 256, h, N);
    gcn_agg_kernel<<<N, 256, 0, stream>>>(
        h, csr_row, csr_efac, rowstart, dnorm, gcn_b + (size_t)l * 256, x_emb, (l < 2) ? 1 : 0, N);
  }
  scores_kernel<<<(N * 64 + 255) / 256, 256, 0, stream>>>(x_emb, attn_w, attn_b, scores, N);
  gse_kernel<<<(N + 255) / 256, 256, 0, stream>>>(batch, gs, ge, N);
  pool_kernel<<<G, 256, 0, stream>>>(x_emb, scores, gs, ge, graph_emb);
  head_kernel<<<G, 256, 0, stream>>>(global_x, graph_emb, gmlp_W1, gmlp_b1, gmlp_W2, gmlp_b2,
                                     fc_W1, fc_b1, fc_W2, fc_b2, (float*)d_out);
}

// Round 2
// 1353.752 us; speedup vs baseline: 1.3648x; 1.3648x over previous
//
#include <hip/hip_runtime.h>

// GraphRegressorV2 — round 2: gse boundary-scan (batch is sorted), bf16 MFMA
// for the 3 GCN GEMMs, h stored bf16 (halves gather traffic), node_embed
// vectorized, scores fused into last agg.

typedef float f32x4 __attribute__((ext_vector_type(4)));
typedef short s16x8 __attribute__((ext_vector_type(8)));

__device__ __forceinline__ unsigned short f2bf(float f) {
  union { float f; unsigned u; } v{f};
  unsigned r = v.u + 0x7fff + ((v.u >> 16) & 1);  // RNE
  return (unsigned short)(r >> 16);
}
__device__ __forceinline__ float bf2f(unsigned short s) {
  union { unsigned u; float f; } v{(unsigned)s << 16};
  return v.f;
}

// ---------------- node embedding (write-BW bound) ----------------
__global__ void node_embed_kernel(const float* __restrict__ x,
                                  const float* __restrict__ coord_W, const float* __restrict__ coord_b,
                                  const float* __restrict__ node_W, const float* __restrict__ node_b,
                                  float* __restrict__ x_emb, int N) {
  int tid = threadIdx.x;
  int node = blockIdx.x * 8 + (tid >> 5);
  if (node >= N) return;
  int ch0 = (tid & 31) * 8;
  const float* xr = x + (size_t)node * 9;
  float out[8];
  if (ch0 < 128) {
    float x0 = xr[0], x1 = xr[1], x2 = xr[2];
    float4 b0 = *(const float4*)&coord_b[ch0];
    float4 b1 = *(const float4*)&coord_b[ch0 + 4];
    float a[8] = {b0.x, b0.y, b0.z, b0.w, b1.x, b1.y, b1.z, b1.w};
#pragma unroll
    for (int k = 0; k < 3; k++) {
      float xv = (k == 0) ? x0 : (k == 1) ? x1 : x2;
      float4 w0 = *(const float4*)&coord_W[k * 128 + ch0];
      float4 w1 = *(const float4*)&coord_W[k * 128 + ch0 + 4];
      a[0] = fmaf(xv, w0.x, a[0]); a[1] = fmaf(xv, w0.y, a[1]);
      a[2] = fmaf(xv, w0.z, a[2]); a[3] = fmaf(xv, w0.w, a[3]);
      a[4] = fmaf(xv, w1.x, a[4]); a[5] = fmaf(xv, w1.y, a[5]);
      a[6] = fmaf(xv, w1.z, a[6]); a[7] = fmaf(xv, w1.w, a[7]);
    }
#pragma unroll
    for (int j = 0; j < 8; j++) out[j] = fmaxf(a[j], 0.f);
  } else {
    int c0 = ch0 - 128;
    float4 b0 = *(const float4*)&node_b[c0];
    float4 b1 = *(const float4*)&node_b[c0 + 4];
    float a[8] = {b0.x, b0.y, b0.z, b0.w, b1.x, b1.y, b1.z, b1.w};
#pragma unroll
    for (int k = 0; k < 6; k++) {
      float xv = xr[3 + k];
      float4 w0 = *(const float4*)&node_W[k * 128 + c0];
      float4 w1 = *(const float4*)&node_W[k * 128 + c0 + 4];
      a[0] = fmaf(xv, w0.x, a[0]); a[1] = fmaf(xv, w0.y, a[1]);
      a[2] = fmaf(xv, w0.z, a[2]); a[3] = fmaf(xv, w0.w, a[3]);
      a[4] = fmaf(xv, w1.x, a[4]); a[5] = fmaf(xv, w1.y, a[5]);
      a[6] = fmaf(xv, w1.z, a[6]); a[7] = fmaf(xv, w1.w, a[7]);
    }
#pragma unroll
    for (int j = 0; j < 8; j++) out[j] = fmaxf(a[j], 0.f);
  }
  float4* dst = (float4*)&x_emb[(size_t)node * 256 + ch0];
  dst[0] = make_float4(out[0], out[1], out[2], out[3]);
  dst[1] = make_float4(out[4], out[5], out[6], out[7]);
}

// ---------------- CSR build ----------------
__global__ void count_kernel(const int* __restrict__ col, int* __restrict__ cnt, int E) {
  int e = blockIdx.x * 256 + threadIdx.x;
  if (e < E) atomicAdd(&cnt[col[e]], 1);
}

__global__ void scan_kernel(const int* __restrict__ cnt, int* __restrict__ rowstart,
                            float* __restrict__ dnorm, int* __restrict__ cursor, int n) {
  __shared__ int sums[1024];
  int t = threadIdx.x;
  int chunk = (n + 1023) / 1024;
  int start = t * chunk;
  int end = min(start + chunk, n);
  int s = 0;
  for (int i = start; i < end; i++) s += cnt[i];
  sums[t] = s;
  for (int off = 1; off < 1024; off <<= 1) {
    __syncthreads();
    int v = (t >= off) ? sums[t - off] : 0;
    __syncthreads();
    sums[t] += v;
  }
  __syncthreads();
  int base = (t == 0) ? 0 : sums[t - 1];
  for (int i = start; i < end; i++) {
    rowstart[i] = base;
    int c = cnt[i];
    base += c;
    dnorm[i] = rsqrtf((float)(c + 1));  // +1 self-loop
    cursor[i] = 0;
  }
  if (t == 1023) rowstart[n] = sums[1023];
}

__global__ void scatter_kernel(const int* __restrict__ row, const int* __restrict__ col,
                               const int* __restrict__ rowstart, int* __restrict__ cursor,
                               const float* __restrict__ dnorm,
                               int* __restrict__ csr_eid, int* __restrict__ csr_row,
                               float* __restrict__ csr_efac, int E) {
  int e = blockIdx.x * 256 + threadIdx.x;
  if (e >= E) return;
  int c = col[e], r = row[e];
  int p = atomicAdd(&cursor[c], 1);
  int slot = rowstart[c] + p;
  csr_eid[slot] = e;
  csr_row[slot] = r;
  csr_efac[slot] = dnorm[r] * dnorm[c];
}

// ---------------- W transpose + bf16 (per-layer, [K][N] -> Wt[N][K]) --------
__global__ void wt_kernel(const float* __restrict__ gcn_W, short* __restrict__ Wt) {
  int idx = blockIdx.x * 256 + threadIdx.x;   // l*65536 + n*256 + k
  int l = idx >> 16;
  int r = idx & 65535;
  int n = r >> 8, k = r & 255;
  Wt[idx] = (short)f2bf(gcn_W[l * 65536 + k * 256 + n]);
}

// ---------------- edge message aggregate (pre-projection) ----------------
__global__ void edge_msg_kernel(const float* __restrict__ edge_attr,
                                const int* __restrict__ csr_eid, const int* __restrict__ rowstart,
                                const float* __restrict__ edge_W, const float* __restrict__ edge_b,
                                float* __restrict__ msg128, int N) {
  int node = blockIdx.x;
  int ch = threadIdx.x;  // 128
  __shared__ float sW[8 * 128];
  __shared__ float sb[128];
  for (int i = ch; i < 8 * 128; i += 128) sW[i] = edge_W[i];
  sb[ch] = edge_b[ch];
  __syncthreads();
  float acc = 0.f;
  int s0 = rowstart[node], s1 = rowstart[node + 1];
  for (int s = s0; s < s1; s++) {
    int e = csr_eid[s];
    const float* ea = edge_attr + (size_t)e * 8;
    float t = sb[ch];
#pragma unroll
    for (int k = 0; k < 8; k++) t = fmaf(ea[k], sW[k * 128 + ch], t);
    acc += fmaxf(t, 0.f);
  }
  msg128[(size_t)node * 128 + ch] = acc;
}

// node_msg[n] = msg128[n] @ proj_W + cnt[n]*proj_b
__global__ void __launch_bounds__(256) proj_gemm_kernel(
    const float* __restrict__ msg128, const float* __restrict__ proj_W,
    const float* __restrict__ proj_b, const int* __restrict__ cnt,
    float* __restrict__ node_msg, int N) {
  __shared__ __align__(16) float xs[16][128];
  int ch = threadIdx.x;
  int n0 = blockIdx.x * 16;
  for (int idx = ch; idx < 16 * 128; idx += 256) {
    int r = idx >> 7, k = idx & 127;
    int n = n0 + r;
    xs[r][k] = (n < N) ? msg128[(size_t)n * 128 + k] : 0.f;
  }
  __syncthreads();
  float acc[16];
#pragma unroll
  for (int r = 0; r < 16; r++) acc[r] = 0.f;
  const float4* xsv = reinterpret_cast<const float4*>(&xs[0][0]);
  for (int k4 = 0; k4 < 32; k4++) {
    float w0 = proj_W[(k4 * 4 + 0) * 256 + ch];
    float w1 = proj_W[(k4 * 4 + 1) * 256 + ch];
    float w2 = proj_W[(k4 * 4 + 2) * 256 + ch];
    float w3 = proj_W[(k4 * 4 + 3) * 256 + ch];
#pragma unroll
    for (int r = 0; r < 16; r++) {
      float4 xv = xsv[r * 32 + k4];
      acc[r] = fmaf(xv.x, w0, acc[r]);
      acc[r] = fmaf(xv.y, w1, acc[r]);
      acc[r] = fmaf(xv.z, w2, acc[r]);
      acc[r] = fmaf(xv.w, w3, acc[r]);
    }
  }
  float pb = proj_b[ch];
#pragma unroll
  for (int r = 0; r < 16; r++) {
    int n = n0 + r;
    if (n < N) node_msg[(size_t)n * 256 + ch] = acc[r] + (float)cnt[n] * pb;
  }
}

// ---------------- GCN GEMM via bf16 MFMA: h = (x_emb+node_msg) @ W ---------
// A staged in LDS (bf16, +8 pad), B = Wt[N][K] bf16 from L2, D -> bf16 h.
__global__ void __launch_bounds__(256) gcn_gemm_mfma(
    const float* __restrict__ X, const float* __restrict__ M,
    const short* __restrict__ Wt, short* __restrict__ Hout, int N) {
  __shared__ short As[64][264];   // row stride 528B = 33*16B: aligned, 2-way-only banks
  int tid = threadIdx.x;
  int n0 = blockIdx.x * 64;
  for (int i = tid; i < 64 * 64; i += 256) {
    int r = i >> 6, c4 = (i & 63) << 2;
    int n = n0 + r;
    float4 xv = make_float4(0.f, 0.f, 0.f, 0.f), mv = xv;
    if (n < N) {
      xv = *(const float4*)&X[(size_t)n * 256 + c4];
      mv = *(const float4*)&M[(size_t)n * 256 + c4];
    }
    union { unsigned u[2]; } pk;
    pk.u[0] = (unsigned)f2bf(xv.x + mv.x) | ((unsigned)f2bf(xv.y + mv.y) << 16);
    pk.u[1] = (unsigned)f2bf(xv.z + mv.z) | ((unsigned)f2bf(xv.w + mv.w) << 16);
    *(uint2*)&As[r][c4] = make_uint2(pk.u[0], pk.u[1]);
  }
  __syncthreads();
  int wave = tid >> 6, lane = tid & 63;
  int mrow = wave * 16 + (lane & 15);
  int kgrp = (lane >> 4) * 8;
  f32x4 acc[16];
#pragma unroll
  for (int i = 0; i < 16; i++) acc[i] = (f32x4){0.f, 0.f, 0.f, 0.f};
  const short* wbase = Wt + (size_t)(lane & 15) * 256 + kgrp;
#pragma unroll
  for (int kk = 0; kk < 8; kk++) {
    s16x8 a = *(const s16x8*)&As[mrow][kk * 32 + kgrp];
#pragma unroll
    for (int nf = 0; nf < 16; nf++) {
      s16x8 b = *(const s16x8*)&wbase[(size_t)nf * 16 * 256 + kk * 32];
      acc[nf] = __builtin_amdgcn_mfma_f32_16x16x32_bf16(a, b, acc[nf], 0, 0, 0);
    }
  }
  int orow0 = wave * 16 + (lane >> 4) * 4;
  int ocol = lane & 15;
#pragma unroll
  for (int nf = 0; nf < 16; nf++) {
#pragma unroll
    for (int r = 0; r < 4; r++) {
      int n = n0 + orow0 + r;
      if (n < N) Hout[(size_t)n * 256 + nf * 16 + ocol] = (short)f2bf(acc[nf][r]);
    }
  }
}

// ---------------- aggregate (+ optional relu, + fused scores on last) ------
__global__ void gcn_agg_kernel(const short* __restrict__ h, const int* __restrict__ csr_row,
                               const float* __restrict__ csr_efac, const int* __restrict__ rowstart,
                               const float* __restrict__ dnorm, const float* __restrict__ b,
                               float* __restrict__ x_emb, int do_relu,
                               const float* __restrict__ attn_w, const float* __restrict__ attn_b,
                               float* __restrict__ scores, int do_scores, int N) {
  __shared__ float red[256];
  int node = blockIdx.x;
  int ch = threadIdx.x;  // 256
  float dn = dnorm[node];
  float acc = bf2f((unsigned short)h[(size_t)node * 256 + ch]) * dn * dn;
  int s0 = rowstart[node], s1 = rowstart[node + 1];
  for (int s = s0; s < s1; s++) {
    int r = csr_row[s];
    float f = csr_efac[s];
    acc = fmaf(bf2f((unsigned short)h[(size_t)r * 256 + ch]), f, acc);
  }
  acc += b[ch];
  if (do_relu) acc = fmaxf(acc, 0.f);
  x_emb[(size_t)node * 256 + ch] = acc;
  if (do_scores) {
    red[ch] = acc * attn_w[ch];
    __syncthreads();
    for (int off = 128; off; off >>= 1) {
      if (ch < off) red[ch] += red[ch + off];
      __syncthreads();
    }
    if (ch == 0) scores[node] = red[0] + attn_b[0];
  }
}

// ---------------- graph segment boundaries (batch is sorted) ----------------
__global__ void gse_kernel(const int* __restrict__ batch, int* __restrict__ gs,
                           int* __restrict__ ge, int N) {
  int i = blockIdx.x * 256 + threadIdx.x;
  if (i >= N) return;
  int g = batch[i];
  if (i == 0) gs[g] = 0;
  else {
    int gp = batch[i - 1];
    if (gp != g) { gs[g] = i; ge[gp] = i - 1; }
  }
  if (i == N - 1) ge[g] = N - 1;
}

__global__ void pool_kernel(const float* __restrict__ x_emb, const float* __restrict__ scores,
                            const int* __restrict__ gs, const int* __restrict__ ge,
                            float* __restrict__ graph_emb) {
  int g = blockIdx.x;
  int tid = threadIdx.x;  // 256
  __shared__ float red[256];
  __shared__ float wts[256];
  int s0 = gs[g], e1 = ge[g];
  if (s0 > e1) {
    graph_emb[(size_t)g * 256 + tid] = 0.f;
    return;
  }
  int s1 = e1 + 1;
  float m = -1e30f;
  for (int i = s0 + tid; i < s1; i += 256) m = fmaxf(m, scores[i]);
  red[tid] = m;
  __syncthreads();
  for (int off = 128; off; off >>= 1) {
    if (tid < off) red[tid] = fmaxf(red[tid], red[tid + off]);
    __syncthreads();
  }
  m = red[0];
  __syncthreads();
  float dsum = 0.f;
  for (int i = s0 + tid; i < s1; i += 256) dsum += expf(scores[i] - m);
  red[tid] = dsum;
  __syncthreads();
  for (int off = 128; off; off >>= 1) {
    if (tid < off) red[tid] += red[tid + off];
    __syncthreads();
  }
  float denom = red[0];
  __syncthreads();
  float acc = 0.f;
  for (int base = s0; base < s1; base += 256) {
    int i = base + tid;
    __syncthreads();
    wts[tid] = (i < s1) ? expf(scores[i] - m) : 0.f;
    __syncthreads();
    int lim = min(256, s1 - base);
    for (int j = 0; j < lim; j++)
      acc = fmaf(x_emb[(size_t)(base + j) * 256 + tid], wts[j], acc);
  }
  graph_emb[(size_t)g * 256 + tid] = acc / denom;
}

// ---------------- head ----------------
__global__ void head_kernel(const float* __restrict__ global_x, const float* __restrict__ graph_emb,
                            const float* __restrict__ W1, const float* __restrict__ b1,
                            const float* __restrict__ W2, const float* __restrict__ b2,
                            const float* __restrict__ fW1, const float* __restrict__ fb1,
                            const float* __restrict__ fW2, const float* __restrict__ fb2,
                            float* __restrict__ out) {
  int g = blockIdx.x;
  int ch = threadIdx.x;  // 256
  __shared__ float t1[256], g2s[256], t3s[256];
  float a = b1[ch];
  const float* gx = global_x + g * 16;
#pragma unroll
  for (int k = 0; k < 16; k++) a = fmaf(gx[k], W1[k * 256 + ch], a);
  t1[ch] = fmaxf(a, 0.f);
  __syncthreads();
  float bb = b2[ch];
  for (int k = 0; k < 256; k++) bb = fmaf(t1[k], W2[k * 256 + ch], bb);
  g2s[ch] = bb;
  __syncthreads();
  float c = fb1[ch];
  const float* ger = graph_emb + (size_t)g * 256;
  for (int k = 0; k < 256; k++) c = fmaf(ger[k], fW1[k * 256 + ch], c);
  for (int k = 0; k < 256; k++) c = fmaf(g2s[k], fW1[(256 + k) * 256 + ch], c);
  t3s[ch] = fmaxf(c, 0.f);
  __syncthreads();
  t1[ch] = t3s[ch] * fW2[ch];
  __syncthreads();
  for (int off = 128; off; off >>= 1) {
    if (ch < off) t1[ch] += t1[ch + off];
    __syncthreads();
  }
  if (ch == 0) out[g] = t1[0] + fb2[0];
}

// ---------------- launch ----------------
extern "C" void kernel_launch(void* const* d_in, const int* in_sizes, int n_in,
                              void* d_out, int out_size, void* d_ws, size_t ws_size,
                              hipStream_t stream) {
  const float* x        = (const float*)d_in[0];
  const int*   ei       = (const int*)d_in[1];
  const int*   batch    = (const int*)d_in[2];
  const float* edge_attr= (const float*)d_in[3];
  const float* global_x = (const float*)d_in[4];
  const float* coord_W  = (const float*)d_in[5];
  const float* coord_b  = (const float*)d_in[6];
  const float* node_W   = (const float*)d_in[7];
  const float* node_b   = (const float*)d_in[8];
  const float* edge_W   = (const float*)d_in[9];
  const float* edge_b   = (const float*)d_in[10];
  const float* proj_W   = (const float*)d_in[11];
  const float* proj_b   = (const float*)d_in[12];
  const float* gcn_W    = (const float*)d_in[13];
  const float* gcn_b    = (const float*)d_in[14];
  const float* attn_w   = (const float*)d_in[15];
  const float* attn_b   = (const float*)d_in[16];
  const float* gmlp_W1  = (const float*)d_in[17];
  const float* gmlp_b1  = (const float*)d_in[18];
  const float* gmlp_W2  = (const float*)d_in[19];
  const float* gmlp_b2  = (const float*)d_in[20];
  const float* fc_W1    = (const float*)d_in[21];
  const float* fc_b1    = (const float*)d_in[22];
  const float* fc_W2    = (const float*)d_in[23];
  const float* fc_b2    = (const float*)d_in[24];

  const int N = in_sizes[0] / 9;
  const int E = in_sizes[3] / 8;
  const int G = in_sizes[4] / 16;

  char* w = (char*)d_ws;
  auto alloc = [&](size_t bytes) -> char* {
    char* p = w;
    w += (bytes + 255) & ~(size_t)255;
    return p;
  };
  float* x_emb    = (float*)alloc((size_t)N * 256 * 4);
  float* node_msg = (float*)alloc((size_t)N * 256 * 4);
  short* h        = (short*)alloc((size_t)N * 256 * 2);   // bf16
  float* msg128   = (float*)alloc((size_t)N * 128 * 4);
  short* Wt       = (short*)alloc((size_t)3 * 256 * 256 * 2);
  int*   cnt      = (int*)alloc((size_t)N * 4);
  int*   rowstart = (int*)alloc((size_t)(N + 1) * 4);
  int*   cursor   = (int*)alloc((size_t)N * 4);
  float* dnorm    = (float*)alloc((size_t)N * 4);
  int*   csr_eid  = (int*)alloc((size_t)E * 4);
  int*   csr_row  = (int*)alloc((size_t)E * 4);
  float* csr_efac = (float*)alloc((size_t)E * 4);
  float* scores   = (float*)alloc((size_t)N * 4);
  int*   gs       = (int*)alloc((size_t)G * 4);
  int*   ge       = (int*)alloc((size_t)G * 4);
  float* graph_emb= (float*)alloc((size_t)G * 256 * 4);

  hipMemsetAsync(cnt, 0, (size_t)N * 4, stream);
  hipMemsetAsync(gs, 0x7f, (size_t)G * 4, stream);
  hipMemsetAsync(ge, 0xff, (size_t)G * 4, stream);

  wt_kernel<<<(3 * 65536) / 256, 256, 0, stream>>>(gcn_W, Wt);
  node_embed_kernel<<<(N + 7) / 8, 256, 0, stream>>>(
      x, coord_W, coord_b, node_W, node_b, x_emb, N);
  count_kernel<<<(E + 255) / 256, 256, 0, stream>>>(ei + E, cnt, E);
  scan_kernel<<<1, 1024, 0, stream>>>(cnt, rowstart, dnorm, cursor, N);
  scatter_kernel<<<(E + 255) / 256, 256, 0, stream>>>(
      ei, ei + E, rowstart, cursor, dnorm, csr_eid, csr_row, csr_efac, E);
  edge_msg_kernel<<<N, 128, 0, stream>>>(edge_attr, csr_eid, rowstart, edge_W, edge_b, msg128, N);
  proj_gemm_kernel<<<(N + 15) / 16, 256, 0, stream>>>(msg128, proj_W, proj_b, cnt, node_msg, N);
  for (int l = 0; l < 3; l++) {
    gcn_gemm_mfma<<<(N + 63) / 64, 256, 0, stream>>>(
        x_emb, node_msg, Wt + (size_t)l * 65536, h, N);
    gcn_agg_kernel<<<N, 256, 0, stream>>>(
        h, csr_row, csr_efac, rowstart, dnorm, gcn_b + (size_t)l * 256, x_emb,
        (l < 2) ? 1 : 0, attn_w, attn_b, scores, (l == 2) ? 1 : 0, N);
  }
  gse_kernel<<<(N + 255) / 256, 256, 0, stream>>>(batch, gs, ge, N);
  pool_kernel<<<G, 256, 0, stream>>>(x_emb, scores, gs, ge, graph_emb);
  head_kernel<<<G, 256, 0, stream>>>(global_x, graph_emb, gmlp_W1, gmlp_b1, gmlp_W2, gmlp_b2,
                                     fc_W1, fc_b1, fc_W2, fc_b2, (float*)d_out);
}

// Round 3
// 1050.294 us; speedup vs baseline: 1.7591x; 1.2889x over previous
//
#include <hip/hip_runtime.h>

// GraphRegressorV2 — round 3: wide-load gather agg (64 lanes/node, uint2 bf16),
// CSR-ordered edge_attr (sequential edge_msg), MFMA proj, all-bf16 GCN chain
// (x0/xin/h/msg128 bf16), fused relu+msg into agg epilogue.

typedef float f32x4 __attribute__((ext_vector_type(4)));
typedef short s16x8 __attribute__((ext_vector_type(8)));

__device__ __forceinline__ unsigned short f2bf(float f) {
  union { float f; unsigned u; } v{f};
  unsigned r = v.u + 0x7fff + ((v.u >> 16) & 1);  // RNE
  return (unsigned short)(r >> 16);
}
__device__ __forceinline__ float bf2f(unsigned short s) {
  union { unsigned u; float f; } v{(unsigned)s << 16};
  return v.f;
}
__device__ __forceinline__ float blo(unsigned u) {
  union { unsigned x; float f; } v{u << 16};
  return v.f;
}
__device__ __forceinline__ float bhi(unsigned u) {
  union { unsigned x; float f; } v{u & 0xffff0000u};
  return v.f;
}
__device__ __forceinline__ unsigned pk2(float a, float b) {
  return (unsigned)f2bf(a) | ((unsigned)f2bf(b) << 16);
}

// ---------------- node embedding -> bf16 x0 ----------------
__global__ void node_embed_kernel(const float* __restrict__ x,
                                  const float* __restrict__ coord_W, const float* __restrict__ coord_b,
                                  const float* __restrict__ node_W, const float* __restrict__ node_b,
                                  short* __restrict__ x0, int N) {
  int tid = threadIdx.x;
  int node = blockIdx.x * 8 + (tid >> 5);
  if (node >= N) return;
  int ch0 = (tid & 31) * 8;
  const float* xr = x + (size_t)node * 9;
  float a[8];
  if (ch0 < 128) {
    float4 b0 = *(const float4*)&coord_b[ch0];
    float4 b1 = *(const float4*)&coord_b[ch0 + 4];
    a[0]=b0.x; a[1]=b0.y; a[2]=b0.z; a[3]=b0.w; a[4]=b1.x; a[5]=b1.y; a[6]=b1.z; a[7]=b1.w;
#pragma unroll
    for (int k = 0; k < 3; k++) {
      float xv = xr[k];
      float4 w0 = *(const float4*)&coord_W[k * 128 + ch0];
      float4 w1 = *(const float4*)&coord_W[k * 128 + ch0 + 4];
      a[0] = fmaf(xv, w0.x, a[0]); a[1] = fmaf(xv, w0.y, a[1]);
      a[2] = fmaf(xv, w0.z, a[2]); a[3] = fmaf(xv, w0.w, a[3]);
      a[4] = fmaf(xv, w1.x, a[4]); a[5] = fmaf(xv, w1.y, a[5]);
      a[6] = fmaf(xv, w1.z, a[6]); a[7] = fmaf(xv, w1.w, a[7]);
    }
  } else {
    int c0 = ch0 - 128;
    float4 b0 = *(const float4*)&node_b[c0];
    float4 b1 = *(const float4*)&node_b[c0 + 4];
    a[0]=b0.x; a[1]=b0.y; a[2]=b0.z; a[3]=b0.w; a[4]=b1.x; a[5]=b1.y; a[6]=b1.z; a[7]=b1.w;
#pragma unroll
    for (int k = 0; k < 6; k++) {
      float xv = xr[3 + k];
      float4 w0 = *(const float4*)&node_W[k * 128 + c0];
      float4 w1 = *(const float4*)&node_W[k * 128 + c0 + 4];
      a[0] = fmaf(xv, w0.x, a[0]); a[1] = fmaf(xv, w0.y, a[1]);
      a[2] = fmaf(xv, w0.z, a[2]); a[3] = fmaf(xv, w0.w, a[3]);
      a[4] = fmaf(xv, w1.x, a[4]); a[5] = fmaf(xv, w1.y, a[5]);
      a[6] = fmaf(xv, w1.z, a[6]); a[7] = fmaf(xv, w1.w, a[7]);
    }
  }
  uint4 o;
  o.x = pk2(fmaxf(a[0], 0.f), fmaxf(a[1], 0.f));
  o.y = pk2(fmaxf(a[2], 0.f), fmaxf(a[3], 0.f));
  o.z = pk2(fmaxf(a[4], 0.f), fmaxf(a[5], 0.f));
  o.w = pk2(fmaxf(a[6], 0.f), fmaxf(a[7], 0.f));
  *(uint4*)&x0[(size_t)node * 256 + ch0] = o;
}

// ---------------- CSR build ----------------
__global__ void count_kernel(const int* __restrict__ col, int* __restrict__ cnt, int E) {
  int e = blockIdx.x * 256 + threadIdx.x;
  if (e < E) atomicAdd(&cnt[col[e]], 1);
}

__global__ void scan_kernel(const int* __restrict__ cnt, int* __restrict__ rowstart,
                            float* __restrict__ dnorm, int* __restrict__ cursor, int n) {
  __shared__ int sums[1024];
  int t = threadIdx.x;
  int chunk = (n + 1023) / 1024;
  int start = t * chunk;
  int end = min(start + chunk, n);
  int s = 0;
  for (int i = start; i < end; i++) s += cnt[i];
  sums[t] = s;
  for (int off = 1; off < 1024; off <<= 1) {
    __syncthreads();
    int v = (t >= off) ? sums[t - off] : 0;
    __syncthreads();
    sums[t] += v;
  }
  __syncthreads();
  int base = (t == 0) ? 0 : sums[t - 1];
  for (int i = start; i < end; i++) {
    rowstart[i] = base;
    int c = cnt[i];
    base += c;
    dnorm[i] = rsqrtf((float)(c + 1));  // +1 self-loop
    cursor[i] = 0;
  }
  if (t == 1023) rowstart[n] = sums[1023];
}

__global__ void scatter_kernel(const int* __restrict__ row, const int* __restrict__ col,
                               const float* __restrict__ edge_attr,
                               const int* __restrict__ rowstart, int* __restrict__ cursor,
                               const float* __restrict__ dnorm,
                               int* __restrict__ csr_row, float* __restrict__ csr_efac,
                               float* __restrict__ ea_sorted, int E) {
  int e = blockIdx.x * 256 + threadIdx.x;
  if (e >= E) return;
  int c = col[e], r = row[e];
  int p = atomicAdd(&cursor[c], 1);
  int slot = rowstart[c] + p;
  csr_row[slot] = r;
  csr_efac[slot] = dnorm[r] * dnorm[c];
  const float4* src = (const float4*)(edge_attr + (size_t)e * 8);
  float4* dst = (float4*)(ea_sorted + (size_t)slot * 8);
  float4 s0 = src[0], s1 = src[1];
  dst[0] = s0;
  dst[1] = s1;
}

// ---------------- weight transpose+bf16: gcnWt[l][n][k], projWt[n][k] -------
__global__ void wt_kernel(const float* __restrict__ gcn_W, const float* __restrict__ proj_W,
                          short* __restrict__ gcnWt, short* __restrict__ projWt) {
  int idx = blockIdx.x * 256 + threadIdx.x;
  if (idx < 3 * 65536) {
    int l = idx >> 16, r = idx & 65535, n = r >> 8, k = r & 255;
    gcnWt[idx] = (short)f2bf(gcn_W[l * 65536 + k * 256 + n]);
  } else {
    int j = idx - 3 * 65536;  // n*128+k
    int n = j >> 7, k = j & 127;
    projWt[j] = (short)f2bf(proj_W[k * 256 + n]);
  }
}

// ---------------- edge message aggregate (sequential, pre-projection) -------
__global__ void edge_msg_kernel(const float* __restrict__ ea_sorted,
                                const int* __restrict__ rowstart,
                                const float* __restrict__ edge_W, const float* __restrict__ edge_b,
                                short* __restrict__ msg128, int N) {
  int node = blockIdx.x;
  int ch = threadIdx.x;  // 128
  __shared__ float sW[8 * 128];
  __shared__ float sb[128];
  for (int i = ch; i < 8 * 128; i += 128) sW[i] = edge_W[i];
  sb[ch] = edge_b[ch];
  __syncthreads();
  float acc = 0.f;
  int s0 = rowstart[node], s1 = rowstart[node + 1];
  const float4* ea4 = (const float4*)ea_sorted;
  for (int s = s0; s < s1; s++) {
    float4 e0 = ea4[(size_t)s * 2];
    float4 e1 = ea4[(size_t)s * 2 + 1];
    float t = sb[ch];
    t = fmaf(e0.x, sW[0 * 128 + ch], t);
    t = fmaf(e0.y, sW[1 * 128 + ch], t);
    t = fmaf(e0.z, sW[2 * 128 + ch], t);
    t = fmaf(e0.w, sW[3 * 128 + ch], t);
    t = fmaf(e1.x, sW[4 * 128 + ch], t);
    t = fmaf(e1.y, sW[5 * 128 + ch], t);
    t = fmaf(e1.z, sW[6 * 128 + ch], t);
    t = fmaf(e1.w, sW[7 * 128 + ch], t);
    acc += fmaxf(t, 0.f);
  }
  msg128[(size_t)node * 128 + ch] = (short)f2bf(acc);
}

// ---------------- proj via MFMA: node_msg = msg128@projW + cnt*pb;
//                  xin0 = bf16(x0 + node_msg) ----------------
__global__ void __launch_bounds__(256) proj_gemm_mfma(
    const short* __restrict__ msg128, const short* __restrict__ projWt,
    const float* __restrict__ proj_b, const int* __restrict__ cnt,
    const short* __restrict__ x0, float* __restrict__ node_msg,
    short* __restrict__ xin0, int N) {
  __shared__ short As[64][136];  // stride 272B: 68 words %32 = 4 -> 2-way only
  int tid = threadIdx.x;
  int n0 = blockIdx.x * 64;
  for (int i = tid; i < 64 * 32; i += 256) {
    int r = i >> 5, c4 = (i & 31) << 2;
    int n = n0 + r;
    uint2 v = make_uint2(0, 0);
    if (n < N) v = *(const uint2*)&msg128[(size_t)n * 128 + c4];
    *(uint2*)&As[r][c4] = v;
  }
  __syncthreads();
  int wave = tid >> 6, lane = tid & 63;
  int mrow = wave * 16 + (lane & 15);
  int kgrp = (lane >> 4) * 8;
  f32x4 acc[16];
#pragma unroll
  for (int i = 0; i < 16; i++) acc[i] = (f32x4){0.f, 0.f, 0.f, 0.f};
  const short* wbase = projWt + (size_t)(lane & 15) * 128 + kgrp;
#pragma unroll
  for (int kk = 0; kk < 4; kk++) {
    s16x8 a = *(const s16x8*)&As[mrow][kk * 32 + kgrp];
#pragma unroll
    for (int nf = 0; nf < 16; nf++) {
      s16x8 b = *(const s16x8*)&wbase[(size_t)nf * 16 * 128 + kk * 32];
      acc[nf] = __builtin_amdgcn_mfma_f32_16x16x32_bf16(a, b, acc[nf], 0, 0, 0);
    }
  }
  int orow0 = wave * 16 + (lane >> 4) * 4;
  int ocol = lane & 15;
#pragma unroll
  for (int nf = 0; nf < 16; nf++) {
    int c = nf * 16 + ocol;
    float pb = proj_b[c];
#pragma unroll
    for (int r = 0; r < 4; r++) {
      int n = n0 + orow0 + r;
      if (n < N) {
        float v = acc[nf][r] + (float)cnt[n] * pb;
        node_msg[(size_t)n * 256 + c] = v;
        xin0[(size_t)n * 256 + c] =
            (short)f2bf(v + bf2f((unsigned short)x0[(size_t)n * 256 + c]));
      }
    }
  }
}

// ---------------- GCN GEMM via bf16 MFMA: h = xin @ W ----------------
__global__ void __launch_bounds__(256) gcn_gemm_mfma(
    const short* __restrict__ Xin, const short* __restrict__ Wt,
    short* __restrict__ Hout, int N) {
  __shared__ short As[64][264];  // stride 528B: 132 words %32 = 4 -> 2-way only
  int tid = threadIdx.x;
  int n0 = blockIdx.x * 64;
  for (int i = tid; i < 64 * 64; i += 256) {
    int r = i >> 6, c4 = (i & 63) << 2;
    int n = n0 + r;
    uint2 v = make_uint2(0, 0);
    if (n < N) v = *(const uint2*)&Xin[(size_t)n * 256 + c4];
    *(uint2*)&As[r][c4] = v;
  }
  __syncthreads();
  int wave = tid >> 6, lane = tid & 63;
  int mrow = wave * 16 + (lane & 15);
  int kgrp = (lane >> 4) * 8;
  f32x4 acc[16];
#pragma unroll
  for (int i = 0; i < 16; i++) acc[i] = (f32x4){0.f, 0.f, 0.f, 0.f};
  const short* wbase = Wt + (size_t)(lane & 15) * 256 + kgrp;
#pragma unroll
  for (int kk = 0; kk < 8; kk++) {
    s16x8 a = *(const s16x8*)&As[mrow][kk * 32 + kgrp];
#pragma unroll
    for (int nf = 0; nf < 16; nf++) {
      s16x8 b = *(const s16x8*)&wbase[(size_t)nf * 16 * 256 + kk * 32];
      acc[nf] = __builtin_amdgcn_mfma_f32_16x16x32_bf16(a, b, acc[nf], 0, 0, 0);
    }
  }
  int orow0 = wave * 16 + (lane >> 4) * 4;
  int ocol = lane & 15;
#pragma unroll
  for (int nf = 0; nf < 16; nf++) {
#pragma unroll
    for (int r = 0; r < 4; r++) {
      int n = n0 + orow0 + r;
      if (n < N) Hout[(size_t)n * 256 + nf * 16 + ocol] = (short)f2bf(acc[nf][r]);
    }
  }
}

// ---------------- aggregate: 64 lanes per node, 4 ch/lane, unroll-4 --------
// last=0: xin = relu(agg+b) + node_msg (bf16).  last=1: x_emb fp32 + scores.
__global__ void __launch_bounds__(256) gcn_agg_kernel(
    const short* __restrict__ h, const int* __restrict__ csr_row,
    const float* __restrict__ csr_efac, const int* __restrict__ rowstart,
    const float* __restrict__ dnorm, const float* __restrict__ b,
    const float* __restrict__ node_msg, short* __restrict__ xin,
    float* __restrict__ x_emb, const float* __restrict__ attn_w,
    const float* __restrict__ attn_b, float* __restrict__ scores,
    int last, int N) {
  int lane = threadIdx.x & 63;
  int node = blockIdx.x * 4 + (threadIdx.x >> 6);
  if (node >= N) return;
  int ch0 = lane << 2;
  size_t rowb = (size_t)node * 256 + ch0;
  float dn = dnorm[node];
  float w = dn * dn;
  uint2 hv = *(const uint2*)&h[rowb];
  float a0 = blo(hv.x) * w, a1 = bhi(hv.x) * w;
  float a2 = blo(hv.y) * w, a3 = bhi(hv.y) * w;
  int s = rowstart[node], s1 = rowstart[node + 1];
  for (; s + 4 <= s1; s += 4) {
    int r0 = csr_row[s], r1 = csr_row[s + 1], r2 = csr_row[s + 2], r3 = csr_row[s + 3];
    float f0 = csr_efac[s], f1 = csr_efac[s + 1], f2 = csr_efac[s + 2], f3 = csr_efac[s + 3];
    uint2 v0 = *(const uint2*)&h[(size_t)r0 * 256 + ch0];
    uint2 v1 = *(const uint2*)&h[(size_t)r1 * 256 + ch0];
    uint2 v2 = *(const uint2*)&h[(size_t)r2 * 256 + ch0];
    uint2 v3 = *(const uint2*)&h[(size_t)r3 * 256 + ch0];
    a0 = fmaf(blo(v0.x), f0, a0); a1 = fmaf(bhi(v0.x), f0, a1);
    a2 = fmaf(blo(v0.y), f0, a2); a3 = fmaf(bhi(v0.y), f0, a3);
    a0 = fmaf(blo(v1.x), f1, a0); a1 = fmaf(bhi(v1.x), f1, a1);
    a2 = fmaf(blo(v1.y), f1, a2); a3 = fmaf(bhi(v1.y), f1, a3);
    a0 = fmaf(blo(v2.x), f2, a0); a1 = fmaf(bhi(v2.x), f2, a1);
    a2 = fmaf(blo(v2.y), f2, a2); a3 = fmaf(bhi(v2.y), f2, a3);
    a0 = fmaf(blo(v3.x), f3, a0); a1 = fmaf(bhi(v3.x), f3, a1);
    a2 = fmaf(blo(v3.y), f3, a2); a3 = fmaf(bhi(v3.y), f3, a3);
  }
  for (; s < s1; s++) {
    int r = csr_row[s];
    float f = csr_efac[s];
    uint2 v = *(const uint2*)&h[(size_t)r * 256 + ch0];
    a0 = fmaf(blo(v.x), f, a0); a1 = fmaf(bhi(v.x), f, a1);
    a2 = fmaf(blo(v.y), f, a2); a3 = fmaf(bhi(v.y), f, a3);
  }
  float4 bv = *(const float4*)&b[ch0];
  a0 += bv.x; a1 += bv.y; a2 += bv.z; a3 += bv.w;
  if (!last) {
    float4 mv = *(const float4*)&node_msg[rowb];
    float y0 = fmaxf(a0, 0.f) + mv.x;
    float y1 = fmaxf(a1, 0.f) + mv.y;
    float y2 = fmaxf(a2, 0.f) + mv.z;
    float y3 = fmaxf(a3, 0.f) + mv.w;
    uint2 o;
    o.x = pk2(y0, y1);
    o.y = pk2(y2, y3);
    *(uint2*)&xin[rowb] = o;
  } else {
    *(float4*)&x_emb[rowb] = make_float4(a0, a1, a2, a3);
    float4 aw = *(const float4*)&attn_w[ch0];
    float p = a0 * aw.x + a1 * aw.y + a2 * aw.z + a3 * aw.w;
#pragma unroll
    for (int off = 32; off; off >>= 1) p += __shfl_down(p, off);
    if (lane == 0) scores[node] = p + attn_b[0];
  }
}

// ---------------- graph segment boundaries (batch sorted) ----------------
__global__ void gse_kernel(const int* __restrict__ batch, int* __restrict__ gs,
                           int* __restrict__ ge, int N) {
  int i = blockIdx.x * 256 + threadIdx.x;
  if (i >= N) return;
  int g = batch[i];
  if (i == 0) gs[g] = 0;
  else {
    int gp = batch[i - 1];
    if (gp != g) { gs[g] = i; ge[gp] = i - 1; }
  }
  if (i == N - 1) ge[g] = N - 1;
}

__global__ void pool_kernel(const float* __restrict__ x_emb, const float* __restrict__ scores,
                            const int* __restrict__ gs, const int* __restrict__ ge,
                            float* __restrict__ graph_emb) {
  int g = blockIdx.x;
  int tid = threadIdx.x;  // 256
  __shared__ float red[256];
  __shared__ float wts[256];
  int s0 = gs[g], e1 = ge[g];
  if (s0 > e1) {
    graph_emb[(size_t)g * 256 + tid] = 0.f;
    return;
  }
  int s1 = e1 + 1;
  float m = -1e30f;
  for (int i = s0 + tid; i < s1; i += 256) m = fmaxf(m, scores[i]);
  red[tid] = m;
  __syncthreads();
  for (int off = 128; off; off >>= 1) {
    if (tid < off) red[tid] = fmaxf(red[tid], red[tid + off]);
    __syncthreads();
  }
  m = red[0];
  __syncthreads();
  float dsum = 0.f;
  for (int i = s0 + tid; i < s1; i += 256) dsum += expf(scores[i] - m);
  red[tid] = dsum;
  __syncthreads();
  for (int off = 128; off; off >>= 1) {
    if (tid < off) red[tid] += red[tid + off];
    __syncthreads();
  }
  float denom = red[0];
  __syncthreads();
  float acc = 0.f;
  for (int base = s0; base < s1; base += 256) {
    int i = base + tid;
    __syncthreads();
    wts[tid] = (i < s1) ? expf(scores[i] - m) : 0.f;
    __syncthreads();
    int lim = min(256, s1 - base);
    for (int j = 0; j < lim; j++)
      acc = fmaf(x_emb[(size_t)(base + j) * 256 + tid], wts[j], acc);
  }
  graph_emb[(size_t)g * 256 + tid] = acc / denom;
}

// ---------------- head ----------------
__global__ void head_kernel(const float* __restrict__ global_x, const float* __restrict__ graph_emb,
                            const float* __restrict__ W1, const float* __restrict__ b1,
                            const float* __restrict__ W2, const float* __restrict__ b2,
                            const float* __restrict__ fW1, const float* __restrict__ fb1,
                            const float* __restrict__ fW2, const float* __restrict__ fb2,
                            float* __restrict__ out) {
  int g = blockIdx.x;
  int ch = threadIdx.x;  // 256
  __shared__ float t1[256], g2s[256], t3s[256];
  float a = b1[ch];
  const float* gx = global_x + g * 16;
#pragma unroll
  for (int k = 0; k < 16; k++) a = fmaf(gx[k], W1[k * 256 + ch], a);
  t1[ch] = fmaxf(a, 0.f);
  __syncthreads();
  float bb = b2[ch];
  for (int k = 0; k < 256; k++) bb = fmaf(t1[k], W2[k * 256 + ch], bb);
  g2s[ch] = bb;
  __syncthreads();
  float c = fb1[ch];
  const float* ger = graph_emb + (size_t)g * 256;
  for (int k = 0; k < 256; k++) c = fmaf(ger[k], fW1[k * 256 + ch], c);
  for (int k = 0; k < 256; k++) c = fmaf(g2s[k], fW1[(256 + k) * 256 + ch], c);
  t3s[ch] = fmaxf(c, 0.f);
  __syncthreads();
  t1[ch] = t3s[ch] * fW2[ch];
  __syncthreads();
  for (int off = 128; off; off >>= 1) {
    if (ch < off) t1[ch] += t1[ch + off];
    __syncthreads();
  }
  if (ch == 0) out[g] = t1[0] + fb2[0];
}

// ---------------- launch ----------------
extern "C" void kernel_launch(void* const* d_in, const int* in_sizes, int n_in,
                              void* d_out, int out_size, void* d_ws, size_t ws_size,
                              hipStream_t stream) {
  const float* x        = (const float*)d_in[0];
  const int*   ei       = (const int*)d_in[1];
  const int*   batch    = (const int*)d_in[2];
  const float* edge_attr= (const float*)d_in[3];
  const float* global_x = (const float*)d_in[4];
  const float* coord_W  = (const float*)d_in[5];
  const float* coord_b  = (const float*)d_in[6];
  const float* node_W   = (const float*)d_in[7];
  const float* node_b   = (const float*)d_in[8];
  const float* edge_W   = (const float*)d_in[9];
  const float* edge_b   = (const float*)d_in[10];
  const float* proj_W   = (const float*)d_in[11];
  const float* proj_b   = (const float*)d_in[12];
  const float* gcn_W    = (const float*)d_in[13];
  const float* gcn_b    = (const float*)d_in[14];
  const float* attn_w   = (const float*)d_in[15];
  const float* attn_b   = (const float*)d_in[16];
  const float* gmlp_W1  = (const float*)d_in[17];
  const float* gmlp_b1  = (const float*)d_in[18];
  const float* gmlp_W2  = (const float*)d_in[19];
  const float* gmlp_b2  = (const float*)d_in[20];
  const float* fc_W1    = (const float*)d_in[21];
  const float* fc_b1    = (const float*)d_in[22];
  const float* fc_W2    = (const float*)d_in[23];
  const float* fc_b2    = (const float*)d_in[24];

  const int N = in_sizes[0] / 9;
  const int E = in_sizes[3] / 8;
  const int G = in_sizes[4] / 16;

  char* w = (char*)d_ws;
  auto alloc = [&](size_t bytes) -> char* {
    char* p = w;
    w += (bytes + 255) & ~(size_t)255;
    return p;
  };
  float* node_msg = (float*)alloc((size_t)N * 256 * 4);
  short* xin      = (short*)alloc((size_t)N * 256 * 2);
  short* h        = (short*)alloc((size_t)N * 256 * 2);   // also msg128 (bf16 N*128)
  short* x0       = (short*)alloc((size_t)N * 256 * 2);
  float* big      = (float*)alloc((size_t)N * 256 * 4);   // ea_sorted then x_emb
  short* msg128   = h;
  float* ea_sorted= big;          // E*8 floats = 25.6 MB <= 51.2 MB
  float* x_emb    = big;          // written by last agg, after edge_msg done
  short* gcnWt    = (short*)alloc((size_t)3 * 65536 * 2);
  short* projWt   = (short*)alloc((size_t)256 * 128 * 2);
  int*   cnt      = (int*)alloc((size_t)N * 4);
  int*   rowstart = (int*)alloc((size_t)(N + 1) * 4);
  int*   cursor   = (int*)alloc((size_t)N * 4);
  float* dnorm    = (float*)alloc((size_t)N * 4);
  int*   csr_row  = (int*)alloc((size_t)E * 4);
  float* csr_efac = (float*)alloc((size_t)E * 4);
  float* scores   = (float*)alloc((size_t)N * 4);
  int*   gs       = (int*)alloc((size_t)G * 4);
  int*   ge       = (int*)alloc((size_t)G * 4);
  float* graph_emb= (float*)alloc((size_t)G * 256 * 4);

  hipMemsetAsync(cnt, 0, (size_t)N * 4, stream);
  hipMemsetAsync(gs, 0x7f, (size_t)G * 4, stream);
  hipMemsetAsync(ge, 0xff, (size_t)G * 4, stream);

  wt_kernel<<<(3 * 65536 + 256 * 128 + 255) / 256, 256, 0, stream>>>(gcn_W, proj_W, gcnWt, projWt);
  node_embed_kernel<<<(N + 7) / 8, 256, 0, stream>>>(
      x, coord_W, coord_b, node_W, node_b, x0, N);
  count_kernel<<<(E + 255) / 256, 256, 0, stream>>>(ei + E, cnt, E);
  scan_kernel<<<1, 1024, 0, stream>>>(cnt, rowstart, dnorm, cursor, N);
  scatter_kernel<<<(E + 255) / 256, 256, 0, stream>>>(
      ei, ei + E, edge_attr, rowstart, cursor, dnorm, csr_row, csr_efac, ea_sorted, E);
  edge_msg_kernel<<<N, 128, 0, stream>>>(ea_sorted, rowstart, edge_W, edge_b, msg128, N);
  proj_gemm_mfma<<<(N + 63) / 64, 256, 0, stream>>>(
      msg128, projWt, proj_b, cnt, x0, node_msg, xin, N);
  for (int l = 0; l < 3; l++) {
    gcn_gemm_mfma<<<(N + 63) / 64, 256, 0, stream>>>(
        xin, gcnWt + (size_t)l * 65536, h, N);
    gcn_agg_kernel<<<(N + 3) / 4, 256, 0, stream>>>(
        h, csr_row, csr_efac, rowstart, dnorm, gcn_b + (size_t)l * 256,
        node_msg, xin, x_emb, attn_w, attn_b, scores, (l == 2) ? 1 : 0, N);
  }
  gse_kernel<<<(N + 255) / 256, 256, 0, stream>>>(batch, gs, ge, N);
  pool_kernel<<<G, 256, 0, stream>>>(x_emb, scores, gs, ge, graph_emb);
  head_kernel<<<G, 256, 0, stream>>>(global_x, graph_emb, gmlp_W1, gmlp_b1, gmlp_W2, gmlp_b2,
                                     fc_W1, fc_b1, fc_W2, fc_b2, (float*)d_out);
}

// Round 4
// 957.518 us; speedup vs baseline: 1.9296x; 1.0969x over previous
//
#include <hip/hip_runtime.h>

// GraphRegressorV2 — round 4: parallel 3-phase scan (was 134µs single-block),
// parallel pooling (softmax-weight pass + chunked atomicAdd pool).
// Rest as round 3: bf16 MFMA GEMMs, wide-load gather agg, CSR-ordered edges.

typedef float f32x4 __attribute__((ext_vector_type(4)));
typedef short s16x8 __attribute__((ext_vector_type(8)));

__device__ __forceinline__ unsigned short f2bf(float f) {
  union { float f; unsigned u; } v{f};
  unsigned r = v.u + 0x7fff + ((v.u >> 16) & 1);  // RNE
  return (unsigned short)(r >> 16);
}
__device__ __forceinline__ float bf2f(unsigned short s) {
  union { unsigned u; float f; } v{(unsigned)s << 16};
  return v.f;
}
__device__ __forceinline__ float blo(unsigned u) {
  union { unsigned x; float f; } v{u << 16};
  return v.f;
}
__device__ __forceinline__ float bhi(unsigned u) {
  union { unsigned x; float f; } v{u & 0xffff0000u};
  return v.f;
}
__device__ __forceinline__ unsigned pk2(float a, float b) {
  return (unsigned)f2bf(a) | ((unsigned)f2bf(b) << 16);
}

// ---------------- node embedding -> bf16 x0 ----------------
__global__ void node_embed_kernel(const float* __restrict__ x,
                                  const float* __restrict__ coord_W, const float* __restrict__ coord_b,
                                  const float* __restrict__ node_W, const float* __restrict__ node_b,
                                  short* __restrict__ x0, int N) {
  int tid = threadIdx.x;
  int node = blockIdx.x * 8 + (tid >> 5);
  if (node >= N) return;
  int ch0 = (tid & 31) * 8;
  const float* xr = x + (size_t)node * 9;
  float a[8];
  if (ch0 < 128) {
    float4 b0 = *(const float4*)&coord_b[ch0];
    float4 b1 = *(const float4*)&coord_b[ch0 + 4];
    a[0]=b0.x; a[1]=b0.y; a[2]=b0.z; a[3]=b0.w; a[4]=b1.x; a[5]=b1.y; a[6]=b1.z; a[7]=b1.w;
#pragma unroll
    for (int k = 0; k < 3; k++) {
      float xv = xr[k];
      float4 w0 = *(const float4*)&coord_W[k * 128 + ch0];
      float4 w1 = *(const float4*)&coord_W[k * 128 + ch0 + 4];
      a[0] = fmaf(xv, w0.x, a[0]); a[1] = fmaf(xv, w0.y, a[1]);
      a[2] = fmaf(xv, w0.z, a[2]); a[3] = fmaf(xv, w0.w, a[3]);
      a[4] = fmaf(xv, w1.x, a[4]); a[5] = fmaf(xv, w1.y, a[5]);
      a[6] = fmaf(xv, w1.z, a[6]); a[7] = fmaf(xv, w1.w, a[7]);
    }
  } else {
    int c0 = ch0 - 128;
    float4 b0 = *(const float4*)&node_b[c0];
    float4 b1 = *(const float4*)&node_b[c0 + 4];
    a[0]=b0.x; a[1]=b0.y; a[2]=b0.z; a[3]=b0.w; a[4]=b1.x; a[5]=b1.y; a[6]=b1.z; a[7]=b1.w;
#pragma unroll
    for (int k = 0; k < 6; k++) {
      float xv = xr[3 + k];
      float4 w0 = *(const float4*)&node_W[k * 128 + c0];
      float4 w1 = *(const float4*)&node_W[k * 128 + c0 + 4];
      a[0] = fmaf(xv, w0.x, a[0]); a[1] = fmaf(xv, w0.y, a[1]);
      a[2] = fmaf(xv, w0.z, a[2]); a[3] = fmaf(xv, w0.w, a[3]);
      a[4] = fmaf(xv, w1.x, a[4]); a[5] = fmaf(xv, w1.y, a[5]);
      a[6] = fmaf(xv, w1.z, a[6]); a[7] = fmaf(xv, w1.w, a[7]);
    }
  }
  uint4 o;
  o.x = pk2(fmaxf(a[0], 0.f), fmaxf(a[1], 0.f));
  o.y = pk2(fmaxf(a[2], 0.f), fmaxf(a[3], 0.f));
  o.z = pk2(fmaxf(a[4], 0.f), fmaxf(a[5], 0.f));
  o.w = pk2(fmaxf(a[6], 0.f), fmaxf(a[7], 0.f));
  *(uint4*)&x0[(size_t)node * 256 + ch0] = o;
}

// ---------------- CSR build: count -> 3-phase parallel scan -> scatter ------
__global__ void count_kernel(const int* __restrict__ col, int* __restrict__ cnt, int E) {
  int e = blockIdx.x * 256 + threadIdx.x;
  if (e < E) atomicAdd(&cnt[col[e]], 1);
}

__global__ void breduce_kernel(const int* __restrict__ cnt, int* __restrict__ partials, int N) {
  __shared__ int red[256];
  int t = threadIdx.x;
  int i = blockIdx.x * 256 + t;
  int v = (i < N) ? cnt[i] : 0;
  red[t] = v;
  __syncthreads();
  for (int off = 128; off; off >>= 1) {
    if (t < off) red[t] += red[t + off];
    __syncthreads();
  }
  if (t == 0) partials[blockIdx.x] = red[0];
}

__global__ void scan_partials_kernel(int* __restrict__ partials, int nb) {
  __shared__ int s[1024];
  int t = threadIdx.x;
  for (int i = t; i < nb; i += 256) s[i] = partials[i];
  __syncthreads();
  if (t == 0) {
    int run = 0;
    for (int i = 0; i < nb; i++) { int c = s[i]; s[i] = run; run += c; }
  }
  __syncthreads();
  for (int i = t; i < nb; i += 256) partials[i] = s[i];
}

__global__ void scan_apply_kernel(const int* __restrict__ cnt, const int* __restrict__ partials,
                                  int* __restrict__ rowstart, float* __restrict__ dnorm,
                                  int* __restrict__ cursor, int N) {
  __shared__ int red[256];
  int t = threadIdx.x;
  int i = blockIdx.x * 256 + t;
  int v = (i < N) ? cnt[i] : 0;
  red[t] = v;
  __syncthreads();
  for (int off = 1; off < 256; off <<= 1) {
    int x = (t >= off) ? red[t - off] : 0;
    __syncthreads();
    red[t] += x;
    __syncthreads();
  }
  if (i < N) {
    int ex = red[t] - v + partials[blockIdx.x];
    rowstart[i] = ex;
    dnorm[i] = rsqrtf((float)(v + 1));  // +1 self-loop
    cursor[i] = 0;
    if (i == N - 1) rowstart[N] = ex + v;
  }
}

__global__ void scatter_kernel(const int* __restrict__ row, const int* __restrict__ col,
                               const float* __restrict__ edge_attr,
                               const int* __restrict__ rowstart, int* __restrict__ cursor,
                               const float* __restrict__ dnorm,
                               int* __restrict__ csr_row, float* __restrict__ csr_efac,
                               float* __restrict__ ea_sorted, int E) {
  int e = blockIdx.x * 256 + threadIdx.x;
  if (e >= E) return;
  int c = col[e], r = row[e];
  int p = atomicAdd(&cursor[c], 1);
  int slot = rowstart[c] + p;
  csr_row[slot] = r;
  csr_efac[slot] = dnorm[r] * dnorm[c];
  const float4* src = (const float4*)(edge_attr + (size_t)e * 8);
  float4* dst = (float4*)(ea_sorted + (size_t)slot * 8);
  float4 s0 = src[0], s1 = src[1];
  dst[0] = s0;
  dst[1] = s1;
}

// ---------------- weight transpose+bf16 ----------------
__global__ void wt_kernel(const float* __restrict__ gcn_W, const float* __restrict__ proj_W,
                          short* __restrict__ gcnWt, short* __restrict__ projWt) {
  int idx = blockIdx.x * 256 + threadIdx.x;
  if (idx < 3 * 65536) {
    int l = idx >> 16, r = idx & 65535, n = r >> 8, k = r & 255;
    gcnWt[idx] = (short)f2bf(gcn_W[l * 65536 + k * 256 + n]);
  } else {
    int j = idx - 3 * 65536;  // n*128+k
    int n = j >> 7, k = j & 127;
    projWt[j] = (short)f2bf(proj_W[k * 256 + n]);
  }
}

// ---------------- edge message aggregate (sequential) ----------------
__global__ void edge_msg_kernel(const float* __restrict__ ea_sorted,
                                const int* __restrict__ rowstart,
                                const float* __restrict__ edge_W, const float* __restrict__ edge_b,
                                short* __restrict__ msg128, int N) {
  int node = blockIdx.x;
  int ch = threadIdx.x;  // 128
  __shared__ float sW[8 * 128];
  __shared__ float sb[128];
  for (int i = ch; i < 8 * 128; i += 128) sW[i] = edge_W[i];
  sb[ch] = edge_b[ch];
  __syncthreads();
  float acc = 0.f;
  int s0 = rowstart[node], s1 = rowstart[node + 1];
  const float4* ea4 = (const float4*)ea_sorted;
  for (int s = s0; s < s1; s++) {
    float4 e0 = ea4[(size_t)s * 2];
    float4 e1 = ea4[(size_t)s * 2 + 1];
    float t = sb[ch];
    t = fmaf(e0.x, sW[0 * 128 + ch], t);
    t = fmaf(e0.y, sW[1 * 128 + ch], t);
    t = fmaf(e0.z, sW[2 * 128 + ch], t);
    t = fmaf(e0.w, sW[3 * 128 + ch], t);
    t = fmaf(e1.x, sW[4 * 128 + ch], t);
    t = fmaf(e1.y, sW[5 * 128 + ch], t);
    t = fmaf(e1.z, sW[6 * 128 + ch], t);
    t = fmaf(e1.w, sW[7 * 128 + ch], t);
    acc += fmaxf(t, 0.f);
  }
  msg128[(size_t)node * 128 + ch] = (short)f2bf(acc);
}

// ---------------- proj via MFMA ----------------
__global__ void __launch_bounds__(256) proj_gemm_mfma(
    const short* __restrict__ msg128, const short* __restrict__ projWt,
    const float* __restrict__ proj_b, const int* __restrict__ cnt,
    const short* __restrict__ x0, float* __restrict__ node_msg,
    short* __restrict__ xin0, int N) {
  __shared__ short As[64][136];
  int tid = threadIdx.x;
  int n0 = blockIdx.x * 64;
  for (int i = tid; i < 64 * 32; i += 256) {
    int r = i >> 5, c4 = (i & 31) << 2;
    int n = n0 + r;
    uint2 v = make_uint2(0, 0);
    if (n < N) v = *(const uint2*)&msg128[(size_t)n * 128 + c4];
    *(uint2*)&As[r][c4] = v;
  }
  __syncthreads();
  int wave = tid >> 6, lane = tid & 63;
  int mrow = wave * 16 + (lane & 15);
  int kgrp = (lane >> 4) * 8;
  f32x4 acc[16];
#pragma unroll
  for (int i = 0; i < 16; i++) acc[i] = (f32x4){0.f, 0.f, 0.f, 0.f};
  const short* wbase = projWt + (size_t)(lane & 15) * 128 + kgrp;
#pragma unroll
  for (int kk = 0; kk < 4; kk++) {
    s16x8 a = *(const s16x8*)&As[mrow][kk * 32 + kgrp];
#pragma unroll
    for (int nf = 0; nf < 16; nf++) {
      s16x8 b = *(const s16x8*)&wbase[(size_t)nf * 16 * 128 + kk * 32];
      acc[nf] = __builtin_amdgcn_mfma_f32_16x16x32_bf16(a, b, acc[nf], 0, 0, 0);
    }
  }
  int orow0 = wave * 16 + (lane >> 4) * 4;
  int ocol = lane & 15;
#pragma unroll
  for (int nf = 0; nf < 16; nf++) {
    int c = nf * 16 + ocol;
    float pb = proj_b[c];
#pragma unroll
    for (int r = 0; r < 4; r++) {
      int n = n0 + orow0 + r;
      if (n < N) {
        float v = acc[nf][r] + (float)cnt[n] * pb;
        node_msg[(size_t)n * 256 + c] = v;
        xin0[(size_t)n * 256 + c] =
            (short)f2bf(v + bf2f((unsigned short)x0[(size_t)n * 256 + c]));
      }
    }
  }
}

// ---------------- GCN GEMM via bf16 MFMA ----------------
__global__ void __launch_bounds__(256) gcn_gemm_mfma(
    const short* __restrict__ Xin, const short* __restrict__ Wt,
    short* __restrict__ Hout, int N) {
  __shared__ short As[64][264];
  int tid = threadIdx.x;
  int n0 = blockIdx.x * 64;
  for (int i = tid; i < 64 * 64; i += 256) {
    int r = i >> 6, c4 = (i & 63) << 2;
    int n = n0 + r;
    uint2 v = make_uint2(0, 0);
    if (n < N) v = *(const uint2*)&Xin[(size_t)n * 256 + c4];
    *(uint2*)&As[r][c4] = v;
  }
  __syncthreads();
  int wave = tid >> 6, lane = tid & 63;
  int mrow = wave * 16 + (lane & 15);
  int kgrp = (lane >> 4) * 8;
  f32x4 acc[16];
#pragma unroll
  for (int i = 0; i < 16; i++) acc[i] = (f32x4){0.f, 0.f, 0.f, 0.f};
  const short* wbase = Wt + (size_t)(lane & 15) * 256 + kgrp;
#pragma unroll
  for (int kk = 0; kk < 8; kk++) {
    s16x8 a = *(const s16x8*)&As[mrow][kk * 32 + kgrp];
#pragma unroll
    for (int nf = 0; nf < 16; nf++) {
      s16x8 b = *(const s16x8*)&wbase[(size_t)nf * 16 * 256 + kk * 32];
      acc[nf] = __builtin_amdgcn_mfma_f32_16x16x32_bf16(a, b, acc[nf], 0, 0, 0);
    }
  }
  int orow0 = wave * 16 + (lane >> 4) * 4;
  int ocol = lane & 15;
#pragma unroll
  for (int nf = 0; nf < 16; nf++) {
#pragma unroll
    for (int r = 0; r < 4; r++) {
      int n = n0 + orow0 + r;
      if (n < N) Hout[(size_t)n * 256 + nf * 16 + ocol] = (short)f2bf(acc[nf][r]);
    }
  }
}

// ---------------- aggregate: 64 lanes/node, 4 ch/lane, unroll-4 ------------
__global__ void __launch_bounds__(256) gcn_agg_kernel(
    const short* __restrict__ h, const int* __restrict__ csr_row,
    const float* __restrict__ csr_efac, const int* __restrict__ rowstart,
    const float* __restrict__ dnorm, const float* __restrict__ b,
    const float* __restrict__ node_msg, short* __restrict__ xin,
    float* __restrict__ x_emb, const float* __restrict__ attn_w,
    const float* __restrict__ attn_b, float* __restrict__ scores,
    int last, int N) {
  int lane = threadIdx.x & 63;
  int node = blockIdx.x * 4 + (threadIdx.x >> 6);
  if (node >= N) return;
  int ch0 = lane << 2;
  size_t rowb = (size_t)node * 256 + ch0;
  float dn = dnorm[node];
  float w = dn * dn;
  uint2 hv = *(const uint2*)&h[rowb];
  float a0 = blo(hv.x) * w, a1 = bhi(hv.x) * w;
  float a2 = blo(hv.y) * w, a3 = bhi(hv.y) * w;
  int s = rowstart[node], s1 = rowstart[node + 1];
  for (; s + 4 <= s1; s += 4) {
    int r0 = csr_row[s], r1 = csr_row[s + 1], r2 = csr_row[s + 2], r3 = csr_row[s + 3];
    float f0 = csr_efac[s], f1 = csr_efac[s + 1], f2 = csr_efac[s + 2], f3 = csr_efac[s + 3];
    uint2 v0 = *(const uint2*)&h[(size_t)r0 * 256 + ch0];
    uint2 v1 = *(const uint2*)&h[(size_t)r1 * 256 + ch0];
    uint2 v2 = *(const uint2*)&h[(size_t)r2 * 256 + ch0];
    uint2 v3 = *(const uint2*)&h[(size_t)r3 * 256 + ch0];
    a0 = fmaf(blo(v0.x), f0, a0); a1 = fmaf(bhi(v0.x), f0, a1);
    a2 = fmaf(blo(v0.y), f0, a2); a3 = fmaf(bhi(v0.y), f0, a3);
    a0 = fmaf(blo(v1.x), f1, a0); a1 = fmaf(bhi(v1.x), f1, a1);
    a2 = fmaf(blo(v1.y), f1, a2); a3 = fmaf(bhi(v1.y), f1, a3);
    a0 = fmaf(blo(v2.x), f2, a0); a1 = fmaf(bhi(v2.x), f2, a1);
    a2 = fmaf(blo(v2.y), f2, a2); a3 = fmaf(bhi(v2.y), f2, a3);
    a0 = fmaf(blo(v3.x), f3, a0); a1 = fmaf(bhi(v3.x), f3, a1);
    a2 = fmaf(blo(v3.y), f3, a2); a3 = fmaf(bhi(v3.y), f3, a3);
  }
  for (; s < s1; s++) {
    int r = csr_row[s];
    float f = csr_efac[s];
    uint2 v = *(const uint2*)&h[(size_t)r * 256 + ch0];
    a0 = fmaf(blo(v.x), f, a0); a1 = fmaf(bhi(v.x), f, a1);
    a2 = fmaf(blo(v.y), f, a2); a3 = fmaf(bhi(v.y), f, a3);
  }
  float4 bv = *(const float4*)&b[ch0];
  a0 += bv.x; a1 += bv.y; a2 += bv.z; a3 += bv.w;
  if (!last) {
    float4 mv = *(const float4*)&node_msg[rowb];
    float y0 = fmaxf(a0, 0.f) + mv.x;
    float y1 = fmaxf(a1, 0.f) + mv.y;
    float y2 = fmaxf(a2, 0.f) + mv.z;
    float y3 = fmaxf(a3, 0.f) + mv.w;
    uint2 o;
    o.x = pk2(y0, y1);
    o.y = pk2(y2, y3);
    *(uint2*)&xin[rowb] = o;
  } else {
    *(float4*)&x_emb[rowb] = make_float4(a0, a1, a2, a3);
    float4 aw = *(const float4*)&attn_w[ch0];
    float p = a0 * aw.x + a1 * aw.y + a2 * aw.z + a3 * aw.w;
#pragma unroll
    for (int off = 32; off; off >>= 1) p += __shfl_down(p, off);
    if (lane == 0) scores[node] = p + attn_b[0];
  }
}

// ---------------- graph segment boundaries (batch sorted) ----------------
__global__ void gse_kernel(const int* __restrict__ batch, int* __restrict__ gs,
                           int* __restrict__ ge, int N) {
  int i = blockIdx.x * 256 + threadIdx.x;
  if (i >= N) return;
  int g = batch[i];
  if (i == 0) gs[g] = 0;
  else {
    int gp = batch[i - 1];
    if (gp != g) { gs[g] = i; ge[gp] = i - 1; }
  }
  if (i == N - 1) ge[g] = N - 1;
}

// per-graph softmax -> per-node weight wnode = exp(s-m)/denom
__global__ void softmax_kernel(const float* __restrict__ scores, const int* __restrict__ gs,
                               const int* __restrict__ ge, float* __restrict__ wnode) {
  int g = blockIdx.x;
  int tid = threadIdx.x;  // 256
  __shared__ float red[256];
  int s0 = gs[g], e1 = ge[g];
  if (s0 > e1) return;
  int s1 = e1 + 1;
  float m = -1e30f;
  for (int i = s0 + tid; i < s1; i += 256) m = fmaxf(m, scores[i]);
  red[tid] = m;
  __syncthreads();
  for (int off = 128; off; off >>= 1) {
    if (tid < off) red[tid] = fmaxf(red[tid], red[tid + off]);
    __syncthreads();
  }
  m = red[0];
  __syncthreads();
  float d = 0.f;
  for (int i = s0 + tid; i < s1; i += 256) d += expf(scores[i] - m);
  red[tid] = d;
  __syncthreads();
  for (int off = 128; off; off >>= 1) {
    if (tid < off) red[tid] += red[tid + off];
    __syncthreads();
  }
  float rd = 1.f / red[0];
  for (int i = s0 + tid; i < s1; i += 256) wnode[i] = expf(scores[i] - m) * rd;
}

// chunked weighted sum with boundary-flush atomics
__global__ void __launch_bounds__(256) pool_sum_kernel(
    const float* __restrict__ x_emb, const float* __restrict__ wnode,
    const int* __restrict__ batch, float* __restrict__ graph_emb, int N) {
  __shared__ int sb[256];
  __shared__ float sw[256];
  int ch = threadIdx.x;
  int i0 = blockIdx.x * 256;
  int lim = min(256, N - i0);
  if (ch < lim) { sb[ch] = batch[i0 + ch]; sw[ch] = wnode[i0 + ch]; }
  __syncthreads();
  int curg = sb[0];
  float acc = 0.f;
  for (int j = 0; j < lim; j++) {
    int g = sb[j];
    if (g != curg) {
      atomicAdd(&graph_emb[(size_t)curg * 256 + ch], acc);
      acc = 0.f;
      curg = g;
    }
    acc = fmaf(x_emb[(size_t)(i0 + j) * 256 + ch], sw[j], acc);
  }
  atomicAdd(&graph_emb[(size_t)curg * 256 + ch], acc);
}

// ---------------- head ----------------
__global__ void head_kernel(const float* __restrict__ global_x, const float* __restrict__ graph_emb,
                            const float* __restrict__ W1, const float* __restrict__ b1,
                            const float* __restrict__ W2, const float* __restrict__ b2,
                            const float* __restrict__ fW1, const float* __restrict__ fb1,
                            const float* __restrict__ fW2, const float* __restrict__ fb2,
                            float* __restrict__ out) {
  int g = blockIdx.x;
  int ch = threadIdx.x;  // 256
  __shared__ float t1[256], g2s[256], t3s[256];
  float a = b1[ch];
  const float* gx = global_x + g * 16;
#pragma unroll
  for (int k = 0; k < 16; k++) a = fmaf(gx[k], W1[k * 256 + ch], a);
  t1[ch] = fmaxf(a, 0.f);
  __syncthreads();
  float bb = b2[ch];
  for (int k = 0; k < 256; k++) bb = fmaf(t1[k], W2[k * 256 + ch], bb);
  g2s[ch] = bb;
  __syncthreads();
  float c = fb1[ch];
  const float* ger = graph_emb + (size_t)g * 256;
  for (int k = 0; k < 256; k++) c = fmaf(ger[k], fW1[k * 256 + ch], c);
  for (int k = 0; k < 256; k++) c = fmaf(g2s[k], fW1[(256 + k) * 256 + ch], c);
  t3s[ch] = fmaxf(c, 0.f);
  __syncthreads();
  t1[ch] = t3s[ch] * fW2[ch];
  __syncthreads();
  for (int off = 128; off; off >>= 1) {
    if (ch < off) t1[ch] += t1[ch + off];
    __syncthreads();
  }
  if (ch == 0) out[g] = t1[0] + fb2[0];
}

// ---------------- launch ----------------
extern "C" void kernel_launch(void* const* d_in, const int* in_sizes, int n_in,
                              void* d_out, int out_size, void* d_ws, size_t ws_size,
                              hipStream_t stream) {
  const float* x        = (const float*)d_in[0];
  const int*   ei       = (const int*)d_in[1];
  const int*   batch    = (const int*)d_in[2];
  const float* edge_attr= (const float*)d_in[3];
  const float* global_x = (const float*)d_in[4];
  const float* coord_W  = (const float*)d_in[5];
  const float* coord_b  = (const float*)d_in[6];
  const float* node_W   = (const float*)d_in[7];
  const float* node_b   = (const float*)d_in[8];
  const float* edge_W   = (const float*)d_in[9];
  const float* edge_b   = (const float*)d_in[10];
  const float* proj_W   = (const float*)d_in[11];
  const float* proj_b   = (const float*)d_in[12];
  const float* gcn_W    = (const float*)d_in[13];
  const float* gcn_b    = (const float*)d_in[14];
  const float* attn_w   = (const float*)d_in[15];
  const float* attn_b   = (const float*)d_in[16];
  const float* gmlp_W1  = (const float*)d_in[17];
  const float* gmlp_b1  = (const float*)d_in[18];
  const float* gmlp_W2  = (const float*)d_in[19];
  const float* gmlp_b2  = (const float*)d_in[20];
  const float* fc_W1    = (const float*)d_in[21];
  const float* fc_b1    = (const float*)d_in[22];
  const float* fc_W2    = (const float*)d_in[23];
  const float* fc_b2    = (const float*)d_in[24];

  const int N = in_sizes[0] / 9;
  const int E = in_sizes[3] / 8;
  const int G = in_sizes[4] / 16;
  const int NB = (N + 255) / 256;  // scan blocks

  char* w = (char*)d_ws;
  auto alloc = [&](size_t bytes) -> char* {
    char* p = w;
    w += (bytes + 255) & ~(size_t)255;
    return p;
  };
  float* node_msg = (float*)alloc((size_t)N * 256 * 4);
  short* xin      = (short*)alloc((size_t)N * 256 * 2);
  short* h        = (short*)alloc((size_t)N * 256 * 2);   // also msg128 (bf16 N*128)
  short* x0       = (short*)alloc((size_t)N * 256 * 2);
  float* big      = (float*)alloc((size_t)N * 256 * 4);   // ea_sorted then x_emb
  short* msg128   = h;
  float* ea_sorted= big;
  float* x_emb    = big;
  short* gcnWt    = (short*)alloc((size_t)3 * 65536 * 2);
  short* projWt   = (short*)alloc((size_t)256 * 128 * 2);
  int*   cnt      = (int*)alloc((size_t)N * 4);
  int*   rowstart = (int*)alloc((size_t)(N + 1) * 4);
  int*   cursor   = (int*)alloc((size_t)N * 4);
  float* dnorm    = (float*)alloc((size_t)N * 4);
  int*   csr_row  = (int*)alloc((size_t)E * 4);
  float* csr_efac = (float*)alloc((size_t)E * 4);
  float* scores   = (float*)alloc((size_t)N * 4);
  float* wnode    = (float*)alloc((size_t)N * 4);
  int*   partials = (int*)alloc((size_t)NB * 4);
  int*   gs       = (int*)alloc((size_t)G * 4);
  int*   ge       = (int*)alloc((size_t)G * 4);
  float* graph_emb= (float*)alloc((size_t)G * 256 * 4);

  hipMemsetAsync(cnt, 0, (size_t)N * 4, stream);
  hipMemsetAsync(gs, 0x7f, (size_t)G * 4, stream);
  hipMemsetAsync(ge, 0xff, (size_t)G * 4, stream);
  hipMemsetAsync(graph_emb, 0, (size_t)G * 256 * 4, stream);

  wt_kernel<<<(3 * 65536 + 256 * 128 + 255) / 256, 256, 0, stream>>>(gcn_W, proj_W, gcnWt, projWt);
  node_embed_kernel<<<(N + 7) / 8, 256, 0, stream>>>(
      x, coord_W, coord_b, node_W, node_b, x0, N);
  count_kernel<<<(E + 255) / 256, 256, 0, stream>>>(ei + E, cnt, E);
  breduce_kernel<<<NB, 256, 0, stream>>>(cnt, partials, N);
  scan_partials_kernel<<<1, 256, 0, stream>>>(partials, NB);
  scan_apply_kernel<<<NB, 256, 0, stream>>>(cnt, partials, rowstart, dnorm, cursor, N);
  scatter_kernel<<<(E + 255) / 256, 256, 0, stream>>>(
      ei, ei + E, edge_attr, rowstart, cursor, dnorm, csr_row, csr_efac, ea_sorted, E);
  edge_msg_kernel<<<N, 128, 0, stream>>>(ea_sorted, rowstart, edge_W, edge_b, msg128, N);
  proj_gemm_mfma<<<(N + 63) / 64, 256, 0, stream>>>(
      msg128, projWt, proj_b, cnt, x0, node_msg, xin, N);
  for (int l = 0; l < 3; l++) {
    gcn_gemm_mfma<<<(N + 63) / 64, 256, 0, stream>>>(
        xin, gcnWt + (size_t)l * 65536, h, N);
    gcn_agg_kernel<<<(N + 3) / 4, 256, 0, stream>>>(
        h, csr_row, csr_efac, rowstart, dnorm, gcn_b + (size_t)l * 256,
        node_msg, xin, x_emb, attn_w, attn_b, scores, (l == 2) ? 1 : 0, N);
  }
  gse_kernel<<<(N + 255) / 256, 256, 0, stream>>>(batch, gs, ge, N);
  softmax_kernel<<<G, 256, 0, stream>>>(scores, gs, ge, wnode);
  pool_sum_kernel<<<NB, 256, 0, stream>>>(x_emb, wnode, batch, graph_emb, N);
  head_kernel<<<G, 256, 0, stream>>>(global_x, graph_emb, gmlp_W1, gmlp_b1, gmlp_W2, gmlp_b2,
                                     fc_W1, fc_b1, fc_W2, fc_b2, (float*)d_out);
}